// Round 2
// baseline (15356.879 us; speedup 1.0000x reference)
//
#include <hip/hip_runtime.h>

typedef __attribute__((ext_vector_type(8))) short short8;     // 8 bf16 = 4 VGPR MFMA frag
typedef __attribute__((ext_vector_type(16))) float f32x16;    // 32x32 acc
typedef __attribute__((ext_vector_type(4))) float f32x4;      // 16x16 acc

#define HID 512
#define BT 32
#define OUTN 12

static __device__ __forceinline__ ushort f2bf(float f) {
    union { float f; uint u; } v; v.f = f;
    uint r = v.u + 0x7FFF + ((v.u >> 16) & 1);   // RNE
    return (ushort)(r >> 16);
}
static __device__ __forceinline__ float bf2f(ushort h) {
    union { float f; uint u; } v; v.u = ((uint)h) << 16; return v.f;
}

// ---- pack H_w (fp32 [512][512]) into bf16 hi/lo, per-wave B-frag stream:
//   dst idx = (((w*32 + ks)*2 + h)*64 + l)*8 + j   ( == t*8 with t = w<<12|ks<<7|h<<6|l )
//   element = H[n = w*32 + (l&31)][k = ks*16 + (l>>5)*8 + j]; h=0 -> hi, h=1 -> lo
__global__ void pack_h(const float* __restrict__ Hw, ushort* __restrict__ Hpk) {
    int t  = blockIdx.x * blockDim.x + threadIdx.x;   // 0..65535
    int l  = t & 63;
    int h  = (t >> 6) & 1;
    int ks = (t >> 7) & 31;
    int w  = t >> 12;                                 // 0..15
    int n  = w * 32 + (l & 31);
    int k0 = ks * 16 + (l >> 5) * 8;
    int base = t * 8;
#pragma unroll
    for (int j = 0; j < 8; ++j) {
        float f = Hw[n * HID + k0 + j];
        ushort hi = f2bf(f);
        Hpk[base + j] = h ? f2bf(f - bf2f(hi)) : hi;
    }
}

// ---- pack O_w (fp32 [12][512]) into bf16, N padded to 16, for 16x16x32:
//   idx = ((ks*64 + l)*8 + j); element = O[col = l&15][k = ks*32 + (l>>4)*8 + j]
__global__ void pack_o(const float* __restrict__ Ow, ushort* __restrict__ op) {
    int t = blockIdx.x * blockDim.x + threadIdx.x;   // 0..1023
    int l  = t & 63;
    int ks = t >> 6;                                 // 0..15
    int col = l & 15;
    int k0  = ks * 32 + (l >> 4) * 8;
    int base = t * 8;
#pragma unroll
    for (int j = 0; j < 8; ++j) {
        float f = (col < OUTN) ? Ow[col * HID + k0 + j] : 0.0f;
        op[base + j] = f2bf(f);
    }
}

// output GEMM for one finished state buffer (waves 0,1 only; w in {0,1})
static __device__ __forceinline__ void out_gemm(const char* zr0, const ushort* __restrict__ Op,
                                                float mbias, int w, int l,
                                                float* __restrict__ out,
                                                int b0, int trow, int T) {
    f32x4 oacc = { mbias, mbias, mbias, mbias };
    const int om    = w * 16 + (l & 15);
    const int obase = om * 1024;
    const int oxor  = (om & 15) << 4;
    const int okb   = (l >> 4) * 16;
#pragma unroll
    for (int ks = 0; ks < 16; ++ks) {
        int off = obase + ((ks * 64 + okb) ^ oxor);
        short8 a  = *(const short8*)(zr0 + off);
        short8 ob = *(const short8*)(Op + ks * 512 + l * 8);
        oacc = __builtin_amdgcn_mfma_f32_16x16x32_bf16(a, ob, oacc, 0, 0, 0);
    }
    int col = l & 15;
    if (col < OUTN) {
#pragma unroll
        for (int r = 0; r < 4; ++r) {
            int mm = w * 16 + (l >> 4) * 4 + r;
            float y = __fdividef(1.0f, 1.0f + __expf(-oacc[r]));
            out[((size_t)(b0 + mm) * T + trow) * OUTN + col] = y;
        }
    }
}

__launch_bounds__(1024, 4)
__global__ void ctrnn_kernel(const float* __restrict__ x,
                             const int*   __restrict__ Tp,
                             const float* __restrict__ Iw,
                             const float* __restrict__ v,
                             const float* __restrict__ mb,
                             const ushort* __restrict__ Hpk,
                             const ushort* __restrict__ Op,
                             float* __restrict__ out) {
    // [buf*2 + (0=hi,1=lo)][m*512 + k] bf16, row pitch 1024B, XOR-swizzled
    __shared__ ushort zs[4][BT * HID];   // 128 KB

    const int T   = Tp[0];
    const int tid = threadIdx.x;
    const int l   = tid & 63;
    const int w   = tid >> 6;            // wave 0..15; owns N cols [w*32, w*32+32)
    const int b0  = blockIdx.x * BT;

    // zero buf 0 (s_0 = 0): zs[0] + zs[1] = 16384 uints
    {
        uint* p = (uint*)&zs[0][0];
#pragma unroll
        for (int i = 0; i < 16; ++i) p[tid + i * 1024] = 0;
    }

    // drive fragment (fp32, exact): drive[m][n] = x[b0+m]*Iw[n] + v[n]
    f32x16 drv;
    {
        int n = w * 32 + (l & 31);
        float iw = Iw[n], vv = v[n];
#pragma unroll
        for (int r = 0; r < 16; ++r) {
            int mm = (r & 3) + 8 * (r >> 2) + 4 * (l >> 5);
            drv[r] = x[b0 + mm] * iw + vv;
        }
    }

    float mbias = 0.f;
    if (w < 2) { int col = l & 15; if (col < OUTN) mbias = mb[col]; }

    // per-wave packed-H base: (w*32 + ks)*1024 + h*512 + l*8 (ushort units)
    const ushort* hbase = Hpk + (size_t)(w * 32) * 1024 + (size_t)l * 8;

    // A-frag addressing (32x32x16): row = l&31, k = ks*16 + (l>>5)*8
    const int am    = l & 31;
    const int abase = am * 1024;
    const int axor  = (am & 15) << 4;
    const int akb   = (l >> 5) * 16;

    __syncthreads();

    for (int t = 0; t < T; ++t) {
        const char* zr0 = (const char*)&zs[(t & 1) * 2 + 0][0];
        const char* zr1 = (const char*)&zs[(t & 1) * 2 + 1][0];
        char* zw0 = (char*)&zs[((t & 1) ^ 1) * 2 + 0][0];
        char* zw1 = (char*)&zs[((t & 1) ^ 1) * 2 + 1][0];

        // ---- phase 3 (waves 0,1): y_{t-1} from s_t (the current read buffer)
        if (w < 2 && t > 0)
            out_gemm(zr0, Op, mbias, w, l, out, b0, t - 1, T);

        // ---- phase 1: u = drive + Hhi*zhi + Hlo*zhi + Hhi*zlo (3-pass bf16)
        f32x16 acc = drv;
        short8 bh = *(const short8*)(hbase);
        short8 bl = *(const short8*)(hbase + 512);
#pragma unroll
        for (int ks = 0; ks < 32; ++ks) {
            short8 bh1, bl1;
            if (ks < 31) {
                bh1 = *(const short8*)(hbase + (size_t)(ks + 1) * 1024);
                bl1 = *(const short8*)(hbase + (size_t)(ks + 1) * 1024 + 512);
            }
            int off = abase + ((ks * 32 + akb) ^ axor);
            short8 ah = *(const short8*)(zr0 + off);
            short8 al = *(const short8*)(zr1 + off);
            acc = __builtin_amdgcn_mfma_f32_32x32x16_bf16(ah, bh, acc, 0, 0, 0);
            acc = __builtin_amdgcn_mfma_f32_32x32x16_bf16(al, bh, acc, 0, 0, 0);
            acc = __builtin_amdgcn_mfma_f32_32x32x16_bf16(ah, bl, acc, 0, 0, 0);
            bh = bh1; bl = bl1;
        }

        // ---- phase 2: z = tanh(u), split hi/lo, write to the OTHER buffer
        {
            int kb = (w * 32 + (l & 31)) * 2;
#pragma unroll
            for (int r = 0; r < 16; ++r) {
                int mm = (r & 3) + 8 * (r >> 2) + 4 * (l >> 5);
                // tanh(u) = 1 - 2/(e^{2u}+1)
                float e = __expf(2.0f * acc[r]);
                float z = 1.0f - __fdividef(2.0f, e + 1.0f);
                ushort h  = f2bf(z);
                ushort lo = f2bf(z - bf2f(h));
                int off = mm * 1024 + (kb ^ ((mm & 15) << 4));
                *(ushort*)(zw0 + off) = h;
                *(ushort*)(zw1 + off) = lo;
            }
        }
        __syncthreads();   // s_{t+1} complete; all reads of s_t done
    }

    // ---- epilogue: y_{T-1} from s_T
    if (w < 2) {
        const char* zr0 = (const char*)&zs[(T & 1) * 2 + 0][0];
        out_gemm(zr0, Op, mbias, w, l, out, b0, T - 1, T);
    }
}

extern "C" void kernel_launch(void* const* d_in, const int* in_sizes, int n_in,
                              void* d_out, int out_size, void* d_ws, size_t ws_size,
                              hipStream_t stream) {
    const float* x  = (const float*)d_in[0];
    const int*   T  = (const int*)d_in[1];
    const float* Iw = (const float*)d_in[2];
    const float* Hw = (const float*)d_in[3];
    const float* Ow = (const float*)d_in[4];
    const float* v  = (const float*)d_in[5];
    const float* m  = (const float*)d_in[6];
    float* out = (float*)d_out;

    ushort* Hpk = (ushort*)d_ws;                 // 16*32*2*512 = 524288 ushorts (1 MB)
    ushort* Op  = Hpk + 16 * 32 * 2 * 512;       // 16*64*8 = 8192 ushorts

    pack_h<<<dim3(256), dim3(256), 0, stream>>>(Hw, Hpk);
    pack_o<<<dim3(4), dim3(256), 0, stream>>>(Ow, Op);
    ctrnn_kernel<<<dim3(256), dim3(1024), 0, stream>>>(x, T, Iw, v, m, Hpk, Op, out);
}

// Round 3
// 3802.928 us; speedup vs baseline: 4.0382x; 4.0382x over previous
//
#include <hip/hip_runtime.h>

typedef __attribute__((ext_vector_type(8))) short short8;     // 8 bf16 = 4 VGPR MFMA frag
typedef __attribute__((ext_vector_type(16))) float f32x16;    // 32x32 acc
typedef __attribute__((ext_vector_type(4))) float f32x4;      // 16x16 acc

#define HID 512
#define BT 32
#define OUTN 12

static __device__ __forceinline__ ushort f2bf(float f) {
    union { float f; uint u; } v; v.f = f;
    uint r = v.u + 0x7FFF + ((v.u >> 16) & 1);   // RNE
    return (ushort)(r >> 16);
}
static __device__ __forceinline__ float bf2f(ushort h) {
    union { float f; uint u; } v; v.u = ((uint)h) << 16; return v.f;
}

// ---- pack H_w (fp32 [512][512]) into bf16 hi/lo, per-wave B-frag stream:
//   dst idx = (((w*32 + ks)*2 + h)*64 + l)*8 + j
//   element = H[n = w*32 + (l&31)][k = ks*16 + (l>>5)*8 + j]; h=0 -> hi, h=1 -> lo
__global__ void pack_h(const float* __restrict__ Hw, ushort* __restrict__ Hpk) {
    int t  = blockIdx.x * blockDim.x + threadIdx.x;   // 0..65535
    int l  = t & 63;
    int h  = (t >> 6) & 1;
    int ks = (t >> 7) & 31;
    int w  = t >> 12;                                 // 0..15
    int n  = w * 32 + (l & 31);
    int k0 = ks * 16 + (l >> 5) * 8;
    int base = t * 8;
#pragma unroll
    for (int j = 0; j < 8; ++j) {
        float f = Hw[n * HID + k0 + j];
        ushort hi = f2bf(f);
        Hpk[base + j] = h ? f2bf(f - bf2f(hi)) : hi;
    }
}

// ---- pack O_w (fp32 [12][512]) into bf16, N padded to 16, for 16x16x32:
//   idx = ((ks*64 + l)*8 + j); element = O[col = l&15][k = ks*32 + (l>>4)*8 + j]
__global__ void pack_o(const float* __restrict__ Ow, ushort* __restrict__ op) {
    int t = blockIdx.x * blockDim.x + threadIdx.x;   // 0..1023
    int l  = t & 63;
    int ks = t >> 6;                                 // 0..15
    int col = l & 15;
    int k0  = ks * 32 + (l >> 4) * 8;
    int base = t * 8;
#pragma unroll
    for (int j = 0; j < 8; ++j) {
        float f = (col < OUTN) ? Ow[col * HID + k0 + j] : 0.0f;
        op[base + j] = f2bf(f);
    }
}

// output GEMM for one finished state buffer (waves 0,1 only; w in {0,1})
static __device__ __forceinline__ void out_gemm(const char* zr0, const ushort* __restrict__ Op,
                                                float mbias, int w, int l,
                                                float* __restrict__ out,
                                                int b0, int trow, int T) {
    f32x4 oacc = { mbias, mbias, mbias, mbias };
    const int om    = w * 16 + (l & 15);
    const int obase = om * 1024;
    const int oxor  = (om & 15) << 4;
    const int okb   = (l >> 4) * 16;
#pragma unroll
    for (int ks = 0; ks < 16; ++ks) {
        int off = obase + ((ks * 64 + okb) ^ oxor);
        short8 a  = *(const short8*)(zr0 + off);
        short8 ob = *(const short8*)(Op + ks * 512 + l * 8);
        oacc = __builtin_amdgcn_mfma_f32_16x16x32_bf16(a, ob, oacc, 0, 0, 0);
    }
    int col = l & 15;
    if (col < OUTN) {
#pragma unroll
        for (int r = 0; r < 4; ++r) {
            int mm = w * 16 + (l >> 4) * 4 + r;
            float y = __fdividef(1.0f, 1.0f + __expf(-oacc[r]));
            out[((size_t)(b0 + mm) * T + trow) * OUTN + col] = y;
        }
    }
}

__launch_bounds__(1024)
__global__ void ctrnn_kernel(const float* __restrict__ x,
                             const int*   __restrict__ Tp,
                             const float* __restrict__ Iw,
                             const float* __restrict__ v,
                             const float* __restrict__ mb,
                             const ushort* __restrict__ Hpk,
                             const ushort* __restrict__ Op,
                             float* __restrict__ out) {
    // [buf*2 + (0=hi,1=lo)][m*512 + k] bf16, row pitch 1024B, XOR-swizzled
    __shared__ ushort zs[4][BT * HID];   // 128 KB

    const int T   = Tp[0];
    const int tid = threadIdx.x;
    const int l   = tid & 63;
    const int w   = tid >> 6;            // wave 0..15; owns N cols [w*32, w*32+32)
    const int b0  = blockIdx.x * BT;

    // zero buf 0 (s_0 = 0): zs[0] + zs[1] = 16384 uints
    {
        uint* p = (uint*)&zs[0][0];
#pragma unroll
        for (int i = 0; i < 16; ++i) p[tid + i * 1024] = 0;
    }

    // drive fragment (fp32, exact): drive[m][n] = x[b0+m]*Iw[n] + v[n]
    f32x16 drv;
    {
        int n = w * 32 + (l & 31);
        float iw = Iw[n], vv = v[n];
#pragma unroll
        for (int r = 0; r < 16; ++r) {
            int mm = (r & 3) + 8 * (r >> 2) + 4 * (l >> 5);
            drv[r] = x[b0 + mm] * iw + vv;
        }
    }

    float mbias = 0.f;
    if (w < 2) { int col = l & 15; if (col < OUTN) mbias = mb[col]; }

    // per-wave packed-H base: (w*32 + ks)*1024 + h*512 + l*8 (ushort units)
    const ushort* hbase = Hpk + (size_t)(w * 32) * 1024 + (size_t)l * 8;

    // A-frag addressing (32x32x16): row = l&31, k = ks*16 + (l>>5)*8
    const int am    = l & 31;
    const int abase = am * 1024;
    const int axor  = (am & 15) << 4;
    const int akb   = (l >> 5) * 16;

    __syncthreads();

    for (int t = 0; t < T; ++t) {
        const char* zr0 = (const char*)&zs[(t & 1) * 2 + 0][0];
        const char* zr1 = (const char*)&zs[(t & 1) * 2 + 1][0];
        char* zw0 = (char*)&zs[((t & 1) ^ 1) * 2 + 0][0];
        char* zw1 = (char*)&zs[((t & 1) ^ 1) * 2 + 1][0];

        // ---- phase 3 (waves 0,1): y_{t-1} from z_t (the current read buffer)
        if (w < 2 && t > 0)
            out_gemm(zr0, Op, mbias, w, l, out, b0, t - 1, T);

        // ---- phase 1: u = drive + Hhi*zhi + Hlo*zhi + Hhi*zlo (3-pass bf16)
        f32x16 acc = drv;
#pragma unroll 8
        for (int ks = 0; ks < 32; ++ks) {
            int off = abase + ((ks * 32 + akb) ^ axor);
            short8 ah = *(const short8*)(zr0 + off);
            short8 al = *(const short8*)(zr1 + off);
            short8 bh = *(const short8*)(hbase + (size_t)ks * 1024);
            short8 bl = *(const short8*)(hbase + (size_t)ks * 1024 + 512);
            acc = __builtin_amdgcn_mfma_f32_32x32x16_bf16(ah, bh, acc, 0, 0, 0);
            acc = __builtin_amdgcn_mfma_f32_32x32x16_bf16(al, bh, acc, 0, 0, 0);
            acc = __builtin_amdgcn_mfma_f32_32x32x16_bf16(ah, bl, acc, 0, 0, 0);
        }

        // ---- phase 2: z = tanh(u), split hi/lo, write to the OTHER buffer
        {
            int kb = (w * 32 + (l & 31)) * 2;
#pragma unroll
            for (int r = 0; r < 16; ++r) {
                int mm = (r & 3) + 8 * (r >> 2) + 4 * (l >> 5);
                // tanh(u) = 1 - 2/(e^{2u}+1)
                float e = __expf(2.0f * acc[r]);
                float z = 1.0f - __fdividef(2.0f, e + 1.0f);
                ushort h  = f2bf(z);
                ushort lo = f2bf(z - bf2f(h));
                int off = mm * 1024 + (kb ^ ((mm & 15) << 4));
                *(ushort*)(zw0 + off) = h;
                *(ushort*)(zw1 + off) = lo;
            }
        }
        __syncthreads();   // z_{t+1} complete; all reads of z_t done
    }

    // ---- epilogue: y_{T-1} from z_T
    if (w < 2) {
        const char* zr0 = (const char*)&zs[(T & 1) * 2 + 0][0];
        out_gemm(zr0, Op, mbias, w, l, out, b0, T - 1, T);
    }
}

extern "C" void kernel_launch(void* const* d_in, const int* in_sizes, int n_in,
                              void* d_out, int out_size, void* d_ws, size_t ws_size,
                              hipStream_t stream) {
    const float* x  = (const float*)d_in[0];
    const int*   T  = (const int*)d_in[1];
    const float* Iw = (const float*)d_in[2];
    const float* Hw = (const float*)d_in[3];
    const float* Ow = (const float*)d_in[4];
    const float* v  = (const float*)d_in[5];
    const float* m  = (const float*)d_in[6];
    float* out = (float*)d_out;

    ushort* Hpk = (ushort*)d_ws;                 // 16*32*2*512 = 524288 ushorts (1 MB)
    ushort* Op  = Hpk + 16 * 32 * 2 * 512;       // 16*64*8 = 8192 ushorts

    pack_h<<<dim3(256), dim3(256), 0, stream>>>(Hw, Hpk);
    pack_o<<<dim3(4), dim3(256), 0, stream>>>(Ow, Op);
    ctrnn_kernel<<<dim3(256), dim3(1024), 0, stream>>>(x, T, Iw, v, m, Hpk, Op, out);
}